// Round 1
// baseline (2621.376 us; speedup 1.0000x reference)
//
#include <hip/hip_runtime.h>

typedef unsigned short u16;
typedef unsigned int   u32;
typedef short bf16x8 __attribute__((ext_vector_type(8)));
typedef float f32x4  __attribute__((ext_vector_type(4)));

#define M_DIM 4096
#define K_DIM 4096
#define N_DIM 16384

// ---------- bf16 split helpers (RNE) ----------
__device__ __forceinline__ u16 f2bf(float f) {
  u32 u = __float_as_uint(f);
  u += 0x7FFFu + ((u >> 16) & 1u);
  return (u16)(u >> 16);
}
__device__ __forceinline__ float bf2f(u16 h) {
  return __uint_as_float(((u32)h) << 16);
}

// ---------- global_load_lds helper ----------
// dest is wave-uniform base + lane*16 (m104); pass the uniform chunk base.
#define GLL16(g, l)                                                            \
  __builtin_amdgcn_global_load_lds(                                            \
      (__attribute__((address_space(1))) void*)(g),                            \
      (__attribute__((address_space(3))) void*)(l), 16, 0, 0)

// ============================================================
// Kernel 1: Ah/Al = hi/lo bf16 split of U * relu(S + delta) (col scale)
// ============================================================
__global__ __launch_bounds__(256) void cvtA_kernel(
    const float* __restrict__ U, const float* __restrict__ S,
    const float* __restrict__ Dl, u16* __restrict__ Ah, u16* __restrict__ Al) {
  const int i = blockIdx.x * 256 + threadIdx.x;  // float4 index over M*K/4
  const float4 u  = reinterpret_cast<const float4*>(U)[i];
  const int   rc  = i & (K_DIM / 4 - 1);         // float4 col within row
  const float4 sv = reinterpret_cast<const float4*>(S)[rc];
  const float4 dv = reinterpret_cast<const float4*>(Dl)[rc];
  const float a0 = u.x * fmaxf(sv.x + dv.x, 0.f);
  const float a1 = u.y * fmaxf(sv.y + dv.y, 0.f);
  const float a2 = u.z * fmaxf(sv.z + dv.z, 0.f);
  const float a3 = u.w * fmaxf(sv.w + dv.w, 0.f);
  const u16 h0 = f2bf(a0), h1 = f2bf(a1), h2 = f2bf(a2), h3 = f2bf(a3);
  reinterpret_cast<ushort4*>(Ah)[i] = make_ushort4(h0, h1, h2, h3);
  reinterpret_cast<ushort4*>(Al)[i] =
      make_ushort4(f2bf(a0 - bf2f(h0)), f2bf(a1 - bf2f(h1)),
                   f2bf(a2 - bf2f(h2)), f2bf(a3 - bf2f(h3)));
}

// ============================================================
// Kernel 2: Bh/Bl = hi/lo bf16 split of Vh, TRANSPOSED to [N][K]
// 64x64 tiles through LDS; coalesced on both sides.
// ============================================================
__global__ __launch_bounds__(256) void cvtB_kernel(
    const float* __restrict__ V, u16* __restrict__ Bh, u16* __restrict__ Bl) {
  __shared__ float t[64][65];
  const int tid = threadIdx.x;
  const int n0 = blockIdx.x * 64;  // gridDim.x = N/64 = 256
  const int k0 = blockIdx.y * 64;  // gridDim.y = K/64 = 64
  {
    const int c4 = tid & 15;   // float4 column
    const int r  = tid >> 4;   // 16 rows per pass
#pragma unroll
    for (int p = 0; p < 4; ++p) {
      const int row = r + p * 16;
      const float4 v = *reinterpret_cast<const float4*>(
          &V[(size_t)(k0 + row) * N_DIM + n0 + c4 * 4]);
      t[row][c4 * 4 + 0] = v.x;
      t[row][c4 * 4 + 1] = v.y;
      t[row][c4 * 4 + 2] = v.z;
      t[row][c4 * 4 + 3] = v.w;
    }
  }
  __syncthreads();
  {
    const int nl = tid >> 2;  // local n (0..63)
    const int q  = tid & 3;   // k quarter (16 k each)
    u32 hv[8], lv[8];
#pragma unroll
    for (int j = 0; j < 8; ++j) {
      const float f0 = t[q * 16 + 2 * j + 0][nl];
      const float f1 = t[q * 16 + 2 * j + 1][nl];
      const u16 h0 = f2bf(f0), h1 = f2bf(f1);
      const u16 e0 = f2bf(f0 - bf2f(h0)), e1 = f2bf(f1 - bf2f(h1));
      hv[j] = (u32)h0 | ((u32)h1 << 16);
      lv[j] = (u32)e0 | ((u32)e1 << 16);
    }
    const size_t base = (size_t)(n0 + nl) * K_DIM + k0 + q * 16;
    *reinterpret_cast<uint4*>(&Bh[base])     = make_uint4(hv[0], hv[1], hv[2], hv[3]);
    *reinterpret_cast<uint4*>(&Bh[base + 8]) = make_uint4(hv[4], hv[5], hv[6], hv[7]);
    *reinterpret_cast<uint4*>(&Bl[base])     = make_uint4(lv[0], lv[1], lv[2], lv[3]);
    *reinterpret_cast<uint4*>(&Bl[base + 8]) = make_uint4(lv[4], lv[5], lv[6], lv[7]);
  }
}

// ============================================================
// Kernel 3: C = Ah@Bh^T + Ah@Bl^T + Al@Bh^T  (3-product bf16 split GEMM)
// 128x128 tile, BK=32, 4 waves (2x2), each wave 64x64 out (4x4 frags).
// LDS is FRAGMENT-MAJOR: tile X, frag g, lane l at X*8192 + g*1024 + l*16.
//   -> ds_read_b128 linear (conflict-free), global_load_lds dest linear.
// A frag: row = g*16 + (lane&15), k = (lane>>4)*8 .. +7 (contiguous).
// ============================================================
__global__ __launch_bounds__(256, 2) void gemm3_kernel(
    const u16* __restrict__ Ah, const u16* __restrict__ Al,
    const u16* __restrict__ Bh, const u16* __restrict__ Bl,
    float* __restrict__ C) {
  __shared__ uint4 ldsbuf[2048];  // 32 KiB: Ah|Al|Bh|Bl tiles of 8 KiB
  char* lds = reinterpret_cast<char*>(ldsbuf);

  const int tid  = threadIdx.x;
  const int lane = tid & 63;
  const int w    = tid >> 6;  // wave 0..3
  const int wm   = w >> 1;
  const int wn   = w & 1;

  // XCD-aware bijective swizzle (nwg = 4096, divisible by 8) [T1, m192]
  const int orig = blockIdx.x;
  const int bid  = (orig & 7) * (4096 >> 3) + (orig >> 3);
  const int mt   = bid >> 7;   // 32 m-tiles
  const int nt   = bid & 127;  // 128 n-tiles (n-major: neighbors share A-panel)
  const int m0   = mt << 7;
  const int n0   = nt << 7;

  const int fr = lane & 15;
  const int k8 = lane >> 4;

  // staging: wave w stages frags {2w, 2w+1} of each of the 4 tiles
  const size_t rowA0 = (size_t)(m0 + (2 * w) * 16 + fr) * K_DIM + k8 * 8;
  const size_t rowA1 = (size_t)(m0 + (2 * w + 1) * 16 + fr) * K_DIM + k8 * 8;
  const size_t rowB0 = (size_t)(n0 + (2 * w) * 16 + fr) * K_DIM + k8 * 8;
  const size_t rowB1 = (size_t)(n0 + (2 * w + 1) * 16 + fr) * K_DIM + k8 * 8;
  const u16* pAh0 = Ah + rowA0;  const u16* pAh1 = Ah + rowA1;
  const u16* pAl0 = Al + rowA0;  const u16* pAl1 = Al + rowA1;
  const u16* pBh0 = Bh + rowB0;  const u16* pBh1 = Bh + rowB1;
  const u16* pBl0 = Bl + rowB0;  const u16* pBl1 = Bl + rowB1;

  char* const dAh = lds + 0     + 2 * w * 1024;
  char* const dAl = lds + 8192  + 2 * w * 1024;
  char* const dBh = lds + 16384 + 2 * w * 1024;
  char* const dBl = lds + 24576 + 2 * w * 1024;

  f32x4 acc[4][4];
  const f32x4 zero = {0.f, 0.f, 0.f, 0.f};
#pragma unroll
  for (int i = 0; i < 4; ++i)
#pragma unroll
    for (int j = 0; j < 4; ++j) acc[i][j] = zero;

  const int aoff = wm * 4 * 1024 + lane * 16;
  const int boff = wn * 4 * 1024 + lane * 16;

  for (int kt = 0; kt < K_DIM / 32; ++kt) {
    GLL16(pAh0, dAh); GLL16(pAh1, dAh + 1024);
    GLL16(pAl0, dAl); GLL16(pAl1, dAl + 1024);
    GLL16(pBh0, dBh); GLL16(pBh1, dBh + 1024);
    GLL16(pBl0, dBl); GLL16(pBl1, dBl + 1024);
    pAh0 += 32; pAh1 += 32; pAl0 += 32; pAl1 += 32;
    pBh0 += 32; pBh1 += 32; pBl0 += 32; pBl1 += 32;
    __syncthreads();  // compiler drains vmcnt before s_barrier -> LDS valid

    bf16x8 ah[4], al[4], bh[4], bl[4];
#pragma unroll
    for (int i = 0; i < 4; ++i) {
      ah[i] = *reinterpret_cast<const bf16x8*>(lds + 0    + aoff + i * 1024);
      al[i] = *reinterpret_cast<const bf16x8*>(lds + 8192 + aoff + i * 1024);
    }
#pragma unroll
    for (int j = 0; j < 4; ++j) {
      bh[j] = *reinterpret_cast<const bf16x8*>(lds + 16384 + boff + j * 1024);
      bl[j] = *reinterpret_cast<const bf16x8*>(lds + 24576 + boff + j * 1024);
    }
#pragma unroll
    for (int i = 0; i < 4; ++i)
#pragma unroll
      for (int j = 0; j < 4; ++j) {
        acc[i][j] = __builtin_amdgcn_mfma_f32_16x16x32_bf16(ah[i], bh[j], acc[i][j], 0, 0, 0);
        acc[i][j] = __builtin_amdgcn_mfma_f32_16x16x32_bf16(ah[i], bl[j], acc[i][j], 0, 0, 0);
        acc[i][j] = __builtin_amdgcn_mfma_f32_16x16x32_bf16(al[i], bh[j], acc[i][j], 0, 0, 0);
      }
    __syncthreads();  // protect LDS before next stage overwrites
  }

  // epilogue: C/D layout col = lane&15, row = (lane>>4)*4 + c  [m89/m91]
  const int rq = lane >> 4;
#pragma unroll
  for (int i = 0; i < 4; ++i) {
    const size_t row = (size_t)(m0 + wm * 64 + i * 16 + rq * 4);
#pragma unroll
    for (int j = 0; j < 4; ++j) {
      float* cp = C + row * N_DIM + (n0 + wn * 64 + j * 16 + fr);
#pragma unroll
      for (int c = 0; c < 4; ++c) cp[(size_t)c * N_DIM] = acc[i][j][c];
    }
  }
}

// ============================================================
// Fallback: plain fp32 tiled GEMM (only if ws too small for bf16 split)
// ============================================================
__global__ __launch_bounds__(256) void gemm_fp32_fallback(
    const float* __restrict__ U, const float* __restrict__ S,
    const float* __restrict__ Dl, const float* __restrict__ V,
    float* __restrict__ C) {
  __shared__ float As[16][64];
  __shared__ float Bs[16][68];
  const int tid = threadIdx.x;
  const int mt = blockIdx.x >> 8;   // 64 m-tiles
  const int nt = blockIdx.x & 255;  // 256 n-tiles
  const int m0 = mt * 64, n0 = nt * 64;
  const int tx = tid & 15, ty = tid >> 4;
  float acc[4][4] = {{0.f}};
  for (int kt = 0; kt < K_DIM; kt += 16) {
    {
      const int row = tid >> 2, kq = (tid & 3) * 4;
      const float4 u  = *reinterpret_cast<const float4*>(&U[(size_t)(m0 + row) * K_DIM + kt + kq]);
      const float4 sv = *reinterpret_cast<const float4*>(&S[kt + kq]);
      const float4 dv = *reinterpret_cast<const float4*>(&Dl[kt + kq]);
      As[kq + 0][row] = u.x * fmaxf(sv.x + dv.x, 0.f);
      As[kq + 1][row] = u.y * fmaxf(sv.y + dv.y, 0.f);
      As[kq + 2][row] = u.z * fmaxf(sv.z + dv.z, 0.f);
      As[kq + 3][row] = u.w * fmaxf(sv.w + dv.w, 0.f);
    }
    {
      const int k = tid >> 4, nq = (tid & 15) * 4;
      const float4 v = *reinterpret_cast<const float4*>(&V[(size_t)(kt + k) * N_DIM + n0 + nq]);
      Bs[k][nq + 0] = v.x; Bs[k][nq + 1] = v.y;
      Bs[k][nq + 2] = v.z; Bs[k][nq + 3] = v.w;
    }
    __syncthreads();
#pragma unroll
    for (int k = 0; k < 16; ++k) {
      float a[4], b[4];
#pragma unroll
      for (int i = 0; i < 4; ++i) a[i] = As[k][ty * 4 + i];
#pragma unroll
      for (int j = 0; j < 4; ++j) b[j] = Bs[k][tx * 4 + j];
#pragma unroll
      for (int i = 0; i < 4; ++i)
#pragma unroll
        for (int j = 0; j < 4; ++j) acc[i][j] = fmaf(a[i], b[j], acc[i][j]);
    }
    __syncthreads();
  }
#pragma unroll
  for (int i = 0; i < 4; ++i)
#pragma unroll
    for (int j = 0; j < 4; ++j)
      C[(size_t)(m0 + ty * 4 + i) * N_DIM + n0 + tx * 4 + j] = acc[i][j];
}

// ============================================================
extern "C" void kernel_launch(void* const* d_in, const int* in_sizes, int n_in,
                              void* d_out, int out_size, void* d_ws, size_t ws_size,
                              hipStream_t stream) {
  const float* U     = (const float*)d_in[0];
  const float* S     = (const float*)d_in[1];
  const float* Vh    = (const float*)d_in[2];
  const float* delta = (const float*)d_in[3];
  // d_in[4] = weight: unused (weight_type=None)
  float* C = (float*)d_out;

  const size_t szA  = (size_t)M_DIM * K_DIM;  // elements
  const size_t szB  = (size_t)N_DIM * K_DIM;
  const size_t need = (2 * szA + 2 * szB) * sizeof(u16);  // 320 MiB

  if (ws_size >= need) {
    u16* Ah = (u16*)d_ws;
    u16* Al = Ah + szA;
    u16* Bh = Al + szA;
    u16* Bl = Bh + szB;
    cvtA_kernel<<<(M_DIM * K_DIM / 4) / 256, 256, 0, stream>>>(U, S, delta, Ah, Al);
    cvtB_kernel<<<dim3(N_DIM / 64, K_DIM / 64), 256, 0, stream>>>(Vh, Bh, Bl);
    gemm3_kernel<<<(M_DIM / 128) * (N_DIM / 128), 256, 0, stream>>>(Ah, Al, Bh, Bl, C);
  } else {
    gemm_fp32_fallback<<<(M_DIM / 64) * (N_DIM / 64), 256, 0, stream>>>(U, S, delta, Vh, C);
  }
}